// Round 1
// baseline (125.939 us; speedup 1.0000x reference)
//
#include <hip/hip_runtime.h>

#define N_POINTS   100000
#define N_EVENTS   1000000
#define N_PAIRS    100000
#define N_RIEMANN  128
#define EPS_F      1e-6f
#define NON_EVENT_W 1.0f

constexpr int BLOCK = 256;
constexpr int EV_BLOCKS = 1024;                       // grid-stride over 1M events
constexpr int PAIR_BLOCKS = (N_PAIRS + BLOCK - 1) / BLOCK;  // 391, one thread/pair
constexpr int TOTAL_BLOCKS = EV_BLOCKS + PAIR_BLOCKS;

__device__ __forceinline__ float block_reduce_sum(float v) {
    // 64-lane wave reduce (CDNA wave = 64)
    #pragma unroll
    for (int off = 32; off > 0; off >>= 1)
        v += __shfl_down(v, off, 64);
    __shared__ float smem[BLOCK / 64];
    const int lane = threadIdx.x & 63;
    const int wid  = threadIdx.x >> 6;
    if (lane == 0) smem[wid] = v;
    __syncthreads();
    float r = 0.f;
    if (threadIdx.x == 0) {
        #pragma unroll
        for (int i = 0; i < BLOCK / 64; ++i) r += smem[i];
    }
    return r;
}

__global__ __launch_bounds__(BLOCK) void partials_kernel(
    const float*  __restrict__ beta,   // (1,1)
    const float2* __restrict__ z0,     // (N_POINTS,2)
    const float2* __restrict__ v0,
    const float2* __restrict__ a0,
    const int*    __restrict__ eu,     // (N_EVENTS,)
    const int*    __restrict__ ev,
    const float*  __restrict__ et,     // (N_EVENTS,)
    const int*    __restrict__ pu,     // (N_PAIRS,)
    const int*    __restrict__ pv,
    const float*  __restrict__ t0p,    // scalar
    const float*  __restrict__ tnp,    // scalar
    float*        __restrict__ partials)
{
    float acc = 0.f;
    const int b = blockIdx.x;

    if (b < EV_BLOCKS) {
        // ---- event term: acc -= sqrt(|zu - zv + EPS|^2) ----
        for (int i = b * BLOCK + threadIdx.x; i < N_EVENTS; i += EV_BLOCKS * BLOCK) {
            const float te = et[i];
            const int iu = eu[i];
            const int iv = ev[i];
            const float2 zu = z0[iu], zvv = z0[iv];
            const float2 vu = v0[iu], vvv = v0[iv];
            const float2 au = a0[iu], avv = a0[iv];
            const float h = 0.5f * te * te;
            const float dx = (zu.x - zvv.x) + (vu.x - vvv.x) * te + (au.x - avv.x) * h + EPS_F;
            const float dy = (zu.y - zvv.y) + (vu.y - vvv.y) * te + (au.y - avv.y) * h + EPS_F;
            acc -= sqrtf(dx * dx + dy * dy);
        }
    } else {
        // ---- non-event term: acc -= W * dt * sum_k exp(b - |dz + dv t + 0.5 da t^2 + EPS|) ----
        const int p = (b - EV_BLOCKS) * BLOCK + threadIdx.x;
        if (p < N_PAIRS) {
            const float t0v = t0p[0];
            const float tnv = tnp[0];
            const float dt  = (tnv - t0v) * (1.0f / N_RIEMANN);
            const float bb  = beta[0];
            const int iu = pu[p];
            const int iv = pv[p];
            const float2 zuu = z0[iu], zvv = z0[iv];
            const float2 vuu = v0[iu], vvv = v0[iv];
            const float2 auu = a0[iu], avv = a0[iv];
            const float dzx = zuu.x - zvv.x, dzy = zuu.y - zvv.y;
            const float dvx = vuu.x - vvv.x, dvy = vuu.y - vvv.y;
            const float dax = auu.x - avv.x, day = auu.y - avv.y;
            float s = 0.f;
            #pragma unroll 4
            for (int k = 0; k < N_RIEMANN; ++k) {
                const float t = t0v + (float)k * (1.0f / N_RIEMANN) * (tnv - t0v);
                const float h = 0.5f * t * t;
                const float dx = dzx + dvx * t + dax * h + EPS_F;
                const float dy = dzy + dvy * t + day * h + EPS_F;
                s += __expf(bb - sqrtf(dx * dx + dy * dy));
            }
            acc = -NON_EVENT_W * dt * s;
        }
    }

    const float r = block_reduce_sum(acc);
    if (threadIdx.x == 0) partials[blockIdx.x] = r;
}

__global__ __launch_bounds__(BLOCK) void reduce_kernel(
    const float* __restrict__ partials,
    const float* __restrict__ beta,
    float*       __restrict__ out)
{
    float acc = 0.f;
    for (int i = threadIdx.x; i < TOTAL_BLOCKS; i += BLOCK) acc += partials[i];
    const float r = block_reduce_sum(acc);
    if (threadIdx.x == 0) out[0] = beta[0] * (float)N_EVENTS + r;
}

extern "C" void kernel_launch(void* const* d_in, const int* in_sizes, int n_in,
                              void* d_out, int out_size, void* d_ws, size_t ws_size,
                              hipStream_t stream) {
    const float*  beta = (const float*)d_in[0];
    const float2* z0   = (const float2*)d_in[1];
    const float2* v0   = (const float2*)d_in[2];
    const float2* a0   = (const float2*)d_in[3];
    const int*    eu   = (const int*)d_in[4];
    const int*    ev   = (const int*)d_in[5];
    const float*  et   = (const float*)d_in[6];
    const int*    pu   = (const int*)d_in[7];
    const int*    pv   = (const int*)d_in[8];
    const float*  t0p  = (const float*)d_in[9];
    const float*  tnp  = (const float*)d_in[10];

    float* partials = (float*)d_ws;           // TOTAL_BLOCKS floats, written before read
    float* out      = (float*)d_out;

    partials_kernel<<<TOTAL_BLOCKS, BLOCK, 0, stream>>>(
        beta, z0, v0, a0, eu, ev, et, pu, pv, t0p, tnp, partials);
    reduce_kernel<<<1, BLOCK, 0, stream>>>(partials, beta, out);
}